// Round 10
// baseline (121.504 us; speedup 1.0000x reference)
//
#include <hip/hip_runtime.h>
#include <math.h>

typedef _Float16 f16;
typedef __attribute__((ext_vector_type(8))) _Float16 f16x8;
typedef __attribute__((ext_vector_type(4))) _Float16 f16x4;
typedef __attribute__((ext_vector_type(4))) float f32x4;

constexpr int BATCH = 32;
constexpr int QL = 1024;
constexpr int KL = 1024;
constexpr int D = 128;
constexpr int BQ = 64;    // query rows per block (16 per wave)
constexpr int BK = 64;    // key rows per tile
constexpr int DKP = 136;  // sK row pitch in halves (272 B)
constexpr int BKP = 72;   // sVT/sP row pitch in halves (144 B)

#define CSC 0.12752863187087177f  // scale * log2(e)

static __device__ __forceinline__ f16x4 pk4(float x, float y, float z, float w) {
  auto a = __builtin_amdgcn_cvt_pkrtz(x, y);
  auto b = __builtin_amdgcn_cvt_pkrtz(z, w);
  f16x4 h;
  h[0] = (f16)a[0]; h[1] = (f16)a[1]; h[2] = (f16)b[0]; h[3] = (f16)b[1];
  return h;
}
static __device__ __forceinline__ f16x8 pk8(float4 u, float4 v) {
  f16x4 a = pk4(u.x, u.y, u.z, u.w);
  f16x4 b = pk4(v.x, v.y, v.z, v.w);
  f16x8 h;
  h[0] = a[0]; h[1] = a[1]; h[2] = a[2]; h[3] = a[3];
  h[4] = b[0]; h[5] = b[1]; h[6] = b[2]; h[7] = b[3];
  return h;
}

template <int CTRL>
static __device__ __forceinline__ float dppf(float v) {
  int x = __float_as_int(v);
  x = __builtin_amdgcn_update_dpp(x, x, CTRL, 0xf, 0xf, false);
  return __int_as_float(x);
}
static __device__ __forceinline__ float rmax16(float v) {
  v = fmaxf(v, dppf<0xB1>(v));
  v = fmaxf(v, dppf<0x4E>(v));
  v = fmaxf(v, dppf<0x141>(v));
  v = fmaxf(v, dppf<0x140>(v));
  return v;
}
static __device__ __forceinline__ float rsum16(float v) {
  v += dppf<0xB1>(v);
  v += dppf<0x4E>(v);
  v += dppf<0x141>(v);
  v += dppf<0x140>(v);
  return v;
}

__global__ __launch_bounds__(256, 2)
void attn_fwd(const float* __restrict__ Qp, const float* __restrict__ Kp,
              const float* __restrict__ Vp, const int* __restrict__ VLp,
              float* __restrict__ Op) {
  __shared__ f16 sK[2][BK][DKP];   // ROW-PERMUTED: pos p holds key (p&15)*4+(p>>4)
  __shared__ f16 sVT[2][D][BKP];   // V tile transposed [d][kk]
  __shared__ f16 sP[4][16][BKP];   // per-wave P tile [row][kk]
  __shared__ int sN[32];
  __shared__ int sB;

  const int tid  = threadIdx.x;
  const int wave = tid >> 6, lane = tid & 63;
  const int l16  = lane & 15, quad = lane >> 4;

  // ---- LPT-balanced static schedule (kept from R9: occupancy +, no cost)
  if (tid < 32) sN[tid] = (VLp[tid] + BK - 1) / BK;
  __syncthreads();
  if (tid < 32) {
    int nb = sN[tid], r = 0;
    #pragma unroll
    for (int k = 0; k < 32; ++k) {
      int nk = sN[k];
      r += (nk > nb) || (nk == nb && k < tid);
    }
    sN[tid] = r;
  }
  __syncthreads();
  const int c = blockIdx.x & 255;
  const int s = (blockIdx.x < 256) ? c : (511 - c);
  if (tid < 32 && sN[tid] == (s >> 4)) sB = tid;
  __syncthreads();
  const int b  = sB;
  const int qt = s & 15;
  const int vl = VLp[b];

  const float* Kb = Kp + (size_t)b * KL * D;
  const float* Vb = Vp + (size_t)b * KL * D;
  const int ntiles = (vl + BK - 1) / BK;

  float4 kreg[8], vreg[8];

  // staging helpers ---------------------------------------------------------
  auto issue_loads = [&](int t) {
    const float4* Kt = (const float4*)(Kb + (size_t)t * BK * D);
    #pragma unroll
    for (int i = 0; i < 4; ++i) {
      int cc = tid + i * 256;
      int row = cc >> 4, d04 = (cc & 15) * 2;
      kreg[2 * i]     = Kt[row * 32 + d04];
      kreg[2 * i + 1] = Kt[row * 32 + d04 + 1];
    }
    const float* Vt = Vb + (size_t)t * BK * D;
    #pragma unroll
    for (int i = 0; i < 2; ++i) {
      int f = tid + i * 256;
      const float* base = Vt + (size_t)((f & 15) * 4) * D + (f >> 4) * 4;
      vreg[i * 4 + 0] = *(const float4*)(base);
      vreg[i * 4 + 1] = *(const float4*)(base + D);
      vreg[i * 4 + 2] = *(const float4*)(base + 2 * D);
      vreg[i * 4 + 3] = *(const float4*)(base + 3 * D);
    }
  };
  auto drain = [&](int buf) {
    #pragma unroll
    for (int i = 0; i < 4; ++i) {
      int cc = tid + i * 256;
      int row = cc >> 4, d0 = (cc & 15) * 8;
      int rp = (row & 3) * 16 + (row >> 2);
      *(f16x8*)&sK[buf][rp][d0] = pk8(kreg[2 * i], kreg[2 * i + 1]);
    }
    #pragma unroll
    for (int i = 0; i < 2; ++i) {
      int f = tid + i * 256;
      int k0 = (f & 15) * 4, d0 = (f >> 4) * 4;
      float4 r0 = vreg[i*4+0], r1 = vreg[i*4+1], r2 = vreg[i*4+2], r3 = vreg[i*4+3];
      *(f16x4*)&sVT[buf][d0 + 0][k0] = pk4(r0.x, r1.x, r2.x, r3.x);
      *(f16x4*)&sVT[buf][d0 + 1][k0] = pk4(r0.y, r1.y, r2.y, r3.y);
      *(f16x4*)&sVT[buf][d0 + 2][k0] = pk4(r0.z, r1.z, r2.z, r3.z);
      *(f16x4*)&sVT[buf][d0 + 3][k0] = pk4(r0.w, r1.w, r2.w, r3.w);
    }
  };

  // ---- Q fragments (A-operand layout)
  const float* Qb = Qp + ((size_t)(b * QL + qt * BQ + wave * 16 + l16)) * D;
  f16x8 qfrag[4];
  #pragma unroll
  for (int kc = 0; kc < 4; ++kc) {
    const float* p = Qb + kc * 32 + quad * 8;
    qfrag[kc] = pk8(*(const float4*)p, *(const float4*)(p + 4));
  }

  auto s_mfma = [&](int buf, f32x4* out) {
    #pragma unroll
    for (int ct = 0; ct < 4; ++ct) {
      f32x4 cacc = (f32x4){0.f, 0.f, 0.f, 0.f};
      #pragma unroll
      for (int kc = 0; kc < 4; ++kc) {
        f16x8 kf = *(const f16x8*)&sK[buf][ct * 16 + l16][kc * 32 + quad * 8];
        cacc = __builtin_amdgcn_mfma_f32_16x16x32_f16(qfrag[kc], kf, cacc, 0, 0, 0);
      }
      out[ct] = cacc;
    }
  };

  float m2[4]   = {-INFINITY, -INFINITY, -INFINITY, -INFINITY};
  float lsum[4] = {0.f, 0.f, 0.f, 0.f};
  f32x4 o[8];
  #pragma unroll
  for (int dt = 0; dt < 8; ++dt) o[dt] = (f32x4){0.f, 0.f, 0.f, 0.f};

  f32x4 sv[4], svn[4];

  // ---- prologue: stage tile0 -> buf0, tile1 -> buf1, compute S(0)
  issue_loads(0);
  drain(0);
  if (ntiles > 1) issue_loads(1);
  __syncthreads();                 // buf0 visible
  s_mfma(0, sv);                   // S(0)
  if (ntiles > 1) drain(1);
  __syncthreads();                 // buf1 visible for iter0's S(1)

  for (int t = 0; t < ntiles; ++t) {
    const int cur = t & 1, nxt = cur ^ 1;

    // ---- S(t+1) [MFMA pipe] — independent of softmax(t) [VALU pipe]
    if (t + 1 < ntiles) s_mfma(nxt, svn);
    // ---- issue loads for tile t+2 (land before B1's vmcnt drain)
    if (t + 2 < ntiles) issue_loads(t + 2);

    // ---- softmax(t): scale/mask/log2-domain, DPP reductions
    #pragma unroll
    for (int ct = 0; ct < 4; ++ct) {
      bool ok = (t * BK + l16 * 4 + ct) < vl;
      #pragma unroll
      for (int r = 0; r < 4; ++r)
        sv[ct][r] = ok ? sv[ct][r] * CSC : -1.0e9f;
    }
    float mnew[4], alpha[4];
    #pragma unroll
    for (int r = 0; r < 4; ++r) {
      float v = fmaxf(fmaxf(sv[0][r], sv[1][r]), fmaxf(sv[2][r], sv[3][r]));
      v = rmax16(v);
      mnew[r]  = fmaxf(m2[r], v);
      alpha[r] = __builtin_amdgcn_exp2f(m2[r] - mnew[r]);
      m2[r]    = mnew[r];
    }
    #pragma unroll
    for (int r = 0; r < 4; ++r) {
      float ls = 0.f;
      #pragma unroll
      for (int ct = 0; ct < 4; ++ct) {
        float p = __builtin_amdgcn_exp2f(sv[ct][r] - mnew[r]);
        sv[ct][r] = p;
        ls += p;
      }
      lsum[r] = lsum[r] * alpha[r] + rsum16(ls);
      *(f16x4*)&sP[wave][quad * 4 + r][l16 * 4] =
          pk4(sv[0][r], sv[1][r], sv[2][r], sv[3][r]);
      #pragma unroll
      for (int dt = 0; dt < 8; ++dt) o[dt][r] *= alpha[r];
    }

    // sP wave-private: in-wave DS order + waitcnt suffices
    asm volatile("s_waitcnt lgkmcnt(0)" ::: "memory");

    // ---- PV(t)
    #pragma unroll
    for (int ks = 0; ks < 2; ++ks) {
      f16x8 pf = *(const f16x8*)&sP[wave][l16][ks * 32 + quad * 8];
      #pragma unroll
      for (int dt = 0; dt < 8; ++dt) {
        f16x8 vf = *(const f16x8*)&sVT[cur][dt * 16 + l16][ks * 32 + quad * 8];
        o[dt] = __builtin_amdgcn_mfma_f32_16x16x32_f16(pf, vf, o[dt], 0, 0, 0);
      }
    }

    __syncthreads();   // B1: all waves' PV reads of sVT[cur] complete
    if (t + 2 < ntiles) drain(cur);   // tile t+2 over tile t's buffer
    __syncthreads();   // B2: staging visible for next iteration's S(t+2)

    #pragma unroll
    for (int ct = 0; ct < 4; ++ct) sv[ct] = svn[ct];
  }

  // ---- epilogue: O /= l, C-layout store
  float* Ob = Op + ((size_t)(b * QL + qt * BQ + wave * 16)) * D;
  #pragma unroll
  for (int r = 0; r < 4; ++r) {
    float inv = 1.0f / lsum[r];
    int row = quad * 4 + r;
    #pragma unroll
    for (int dt = 0; dt < 8; ++dt)
      Ob[(size_t)row * D + dt * 16 + l16] = o[dt][r] * inv;
  }
}

extern "C" void kernel_launch(void* const* d_in, const int* in_sizes, int n_in,
                              void* d_out, int out_size, void* d_ws, size_t ws_size,
                              hipStream_t stream) {
  const float* Qp = (const float*)d_in[0];
  const float* Kp = (const float*)d_in[1];
  const float* Vp = (const float*)d_in[2];
  const int*   VL = (const int*)d_in[3];
  float* Op = (float*)d_out;

  attn_fwd<<<dim3(QL / BQ * BATCH), dim3(256), 0, stream>>>(Qp, Kp, Vp, VL, Op);
}